// Round 2
// baseline (382.661 us; speedup 1.0000x reference)
//
#include <hip/hip_runtime.h>

// LSTMClassifier: B=1024, T=1024, H=16, C=6
// MFMA-batched recurrence: one wave handles a 16-batch tile.
//   D_q[unit,batch] = (k_q*W_hh_q) @ h + (k_q*(W_ih*x_t + bias))   (one
//   v_mfma_f32_16x16x16_f16 per gate q = i,f,g,o; A=const weights,
//   B=h tile f16, C=per-step x contribution in f32)
// Layout identity: D frag (col=lane&15, row=(lane>>4)*4+r) ==
// B frag (col=lane&15, k=(lane>>4)*4+e)  ->  h computed in D layout feeds
// next step's B operand via two in-lane v_cvt_pkrtz. ZERO cross-lane ops
// in the serial loop (old kernel: movdpp+pack+8 readlane+3 quad-bcast per
// step, all hazard-stalled at 1 wave/SIMD).
// Per lane: 4 cells (units 4*kg..4*kg+3 of batch lane&15). Gate math is
// 4-wide independent -> exp2/rcp pipeline instead of serializing.
// Scale folding (same as old baseline): sigmoid(a)=1/(1+exp2(-L*a)) with
// -L folded into W/b for i,f,o; -2L for g so r_g=(tanh+1)/2; cell kept as
// cs=-2L*c so tanh(c)=2/(1+exp2(cs))-1.
// R1 fix: cvt_pkrtz returns __fp16 vectors -> use __fp16 ext-vector types
// for all f16 fragments (clang rejects _Float16<->__fp16 vector mixing).

#define T_LEN 1024
#define BATCH 1024

typedef __fp16 h4 __attribute__((ext_vector_type(4)));
typedef __fp16 h2 __attribute__((ext_vector_type(2)));
typedef float f4 __attribute__((ext_vector_type(4)));

__device__ __forceinline__ float fexp2(float x) {
#if __has_builtin(__builtin_amdgcn_exp2f)
    return __builtin_amdgcn_exp2f(x);
#else
    return exp2f(x);
#endif
}
__device__ __forceinline__ float frcp(float x) {
#if __has_builtin(__builtin_amdgcn_rcpf)
    return __builtin_amdgcn_rcpf(x);
#else
    return 1.0f / x;
#endif
}

__launch_bounds__(64)
__global__ void lstm_cls_kernel(const float* __restrict__ x,
                                const float* __restrict__ W_ih,
                                const float* __restrict__ W_hh,
                                const float* __restrict__ b_ih,
                                const float* __restrict__ b_hh,
                                const float* __restrict__ W_fc,
                                const float* __restrict__ b_fc,
                                float* __restrict__ out) {
    const int lane = threadIdx.x & 63;
    const int col  = lane & 15;          // batch within tile == matrix col
    const int kg   = lane >> 4;          // k/row group (0..3)
    const int b    = blockIdx.x * 16 + col;

    const float LOG2E = 1.44269504088896340736f;
    const float NEGL  = -LOG2E;
    const float NEG2L = -2.0f * LOG2E;
    const float POS2L =  2.0f * LOG2E;
    const float NEG4L = -4.0f * LOG2E;

    // ---- loop-invariant A fragments: A[m=col][k=4*kg+e] = k_q*W_hh[q*16+m][k]
    h4 Ai, Af, Ag, Ao;
    {
        const float* w0 = W_hh + (0 * 16 + col) * 16 + 4 * kg;  // gate i
        const float* w1 = W_hh + (1 * 16 + col) * 16 + 4 * kg;  // gate f
        const float* w2 = W_hh + (2 * 16 + col) * 16 + 4 * kg;  // gate g
        const float* w3 = W_hh + (3 * 16 + col) * 16 + 4 * kg;  // gate o
        #pragma unroll
        for (int e = 0; e < 4; ++e) {
            Ai[e] = (__fp16)(NEGL  * w0[e]);
            Af[e] = (__fp16)(NEGL  * w1[e]);
            Ag[e] = (__fp16)(NEG2L * w2[e]);
            Ao[e] = (__fp16)(NEGL  * w3[e]);
        }
    }

    // ---- loop-invariant C-building constants: row = q*16 + 4*kg + r ----
    f4 KWi, KWf, KWg, KWo, KBi, KBf, KBg, KBo;
    {
        const int r0 = 4 * kg;
        #pragma unroll
        for (int r = 0; r < 4; ++r) {
            const int rowi = 0 * 16 + r0 + r;
            const int rowf = 1 * 16 + r0 + r;
            const int rowg = 2 * 16 + r0 + r;
            const int rowo = 3 * 16 + r0 + r;
            KWi[r] = NEGL  * W_ih[rowi];  KBi[r] = NEGL  * (b_ih[rowi] + b_hh[rowi]);
            KWf[r] = NEGL  * W_ih[rowf];  KBf[r] = NEGL  * (b_ih[rowf] + b_hh[rowf]);
            KWg[r] = NEG2L * W_ih[rowg];  KBg[r] = NEG2L * (b_ih[rowg] + b_hh[rowg]);
            KWo[r] = NEGL  * W_ih[rowo];  KBo[r] = NEGL  * (b_ih[rowo] + b_hh[rowo]);
        }
    }

    // ---- state ----
    f4 cs = {0.0f, 0.0f, 0.0f, 0.0f};   // cs = -2*log2e * c
    f4 hn = {0.0f, 0.0f, 0.0f, 0.0f};   // h (f32, D layout)
    h4 hb = {(__fp16)0.0f, (__fp16)0.0f, (__fp16)0.0f, (__fp16)0.0f};

    // x prefetch: per-lane float4 of own batch row, 2 groups (8 steps) ahead
    const float* xrow = x + (size_t)b * T_LEN;
    f4 xcur = *(const f4*)(xrow);
    f4 xnxt = *(const f4*)(xrow + 4);

    for (int g4 = 0; g4 < T_LEN / 4; ++g4) {
        const int gi = (g4 + 2 < T_LEN / 4) ? (g4 + 2) : (T_LEN / 4 - 1);
        const f4 xfut = *(const f4*)(xrow + gi * 4);

        #pragma unroll
        for (int s = 0; s < 4; ++s) {
            const float xb = xcur[s];

            // C frags: x contribution + bias (off the h critical path)
            f4 ci, cf, cg, co;
            #pragma unroll
            for (int r = 0; r < 4; ++r) {
                cg[r] = fmaf(xb, KWg[r], KBg[r]);
                ci[r] = fmaf(xb, KWi[r], KBi[r]);
                cf[r] = fmaf(xb, KWf[r], KBf[r]);
                co[r] = fmaf(xb, KWo[r], KBo[r]);
            }

            // 4 independent MFMAs: D_q = A_q @ h + C_q  (g first: longest use)
            const f4 dg = __builtin_amdgcn_mfma_f32_16x16x16f16(Ag, hb, cg, 0, 0, 0);
            const f4 di = __builtin_amdgcn_mfma_f32_16x16x16f16(Ai, hb, ci, 0, 0, 0);
            const f4 df = __builtin_amdgcn_mfma_f32_16x16x16f16(Af, hb, cf, 0, 0, 0);
            const f4 dq = __builtin_amdgcn_mfma_f32_16x16x16f16(Ao, hb, co, 0, 0, 0);

            // activations: 16 independent sigmoid-form values -> pipelined
            f4 rg, ri, rf, ro;
            #pragma unroll
            for (int r = 0; r < 4; ++r) rg[r] = frcp(1.0f + fexp2(dg[r]));
            #pragma unroll
            for (int r = 0; r < 4; ++r) ri[r] = frcp(1.0f + fexp2(di[r]));
            #pragma unroll
            for (int r = 0; r < 4; ++r) rf[r] = frcp(1.0f + fexp2(df[r]));
            #pragma unroll
            for (int r = 0; r < 4; ++r) ro[r] = frcp(1.0f + fexp2(dq[r]));

            // cell + hidden update (4 independent cells per lane)
            #pragma unroll
            for (int r = 0; r < 4; ++r) {
                const float term = ri[r] * fmaf(rg[r], NEG4L, POS2L);
                cs[r] = fmaf(rf[r], cs[r], term);
                const float rt = frcp(1.0f + fexp2(cs[r]));
                hn[r] = fmaf(ro[r] + ro[r], rt, -ro[r]);
            }

            // h -> f16 B fragment, in-lane (D layout == B layout)
            const h2 plo = __builtin_amdgcn_cvt_pkrtz(hn[0], hn[1]);
            const h2 phi = __builtin_amdgcn_cvt_pkrtz(hn[2], hn[3]);
            hb = __builtin_shufflevector(plo, phi, 0, 1, 2, 3);
        }
        xcur = xnxt;
        xnxt = xfut;
    }

    // ---- epilogue: logits[b, cc] = b_fc[cc] + W_fc[cc,:] . h[:,b] ----
    __shared__ float hs[16][17];
    #pragma unroll
    for (int r = 0; r < 4; ++r) hs[col][4 * kg + r] = hn[r];
    __syncthreads();

    {
        const int cc = kg;  // classes 0..3
        float acc = b_fc[cc];
        const float* wf = W_fc + cc * 16;
        #pragma unroll
        for (int u = 0; u < 16; ++u) acc = fmaf(wf[u], hs[col][u], acc);
        out[b * 6 + cc] = acc;
    }
    if (kg < 2) {
        const int cc = kg + 4;  // classes 4..5
        float acc = b_fc[cc];
        const float* wf = W_fc + cc * 16;
        #pragma unroll
        for (int u = 0; u < 16; ++u) acc = fmaf(wf[u], hs[col][u], acc);
        out[b * 6 + cc] = acc;
    }
}

extern "C" void kernel_launch(void* const* d_in, const int* in_sizes, int n_in,
                              void* d_out, int out_size, void* d_ws, size_t ws_size,
                              hipStream_t stream) {
    const float* x    = (const float*)d_in[0];
    const float* W_ih = (const float*)d_in[1];
    const float* W_hh = (const float*)d_in[2];
    const float* b_ih = (const float*)d_in[3];
    const float* b_hh = (const float*)d_in[4];
    const float* W_fc = (const float*)d_in[5];
    const float* b_fc = (const float*)d_in[6];
    float* out = (float*)d_out;

    lstm_cls_kernel<<<BATCH / 16, 64, 0, stream>>>(x, W_ih, W_hh, b_ih, b_hh,
                                                   W_fc, b_fc, out);
}

// Round 3
// 235.123 us; speedup vs baseline: 1.6275x; 1.6275x over previous
//
#include <hip/hip_runtime.h>

// LSTMClassifier: B=1024, T=1024, H=16, C=6
// V3: scalar recurrence (1 batch/wave, 1024 waves = 1/SIMD) with broadcast-A
// MFMA matvec replacing the readlane/fdot2 front-end.
//   D_q[m][n] = sum_k h[k] * (s_q*W_hh[q*16+n][k]) + C_q[m]   (4x 16x16x16f16)
//   A[m][k] = h[k] (replicated rows)  -> every lane's D col = its unit:
//   all 64 lanes hold all 4 gate preacts for unit (lane&15), 4x redundant
//   over row-group g = lane>>4. Entire cell update is LANE-LOCAL.
// Next-step A-frag gather: pack h pairs (quad_perm swap + cvt_pkrtz), then
// 2 ds_bpermute with LOOP-INVARIANT byte addrs 16g / 16g+8 (group g pulls
// packed pairs P_{2g}, P_{2g+1} = h[4g..4g+3]). Replaces 8 hazard-stalled
// v_readlane + 4-deep fdot2 chain of the 156us baseline.
// x contribution rides in C[0] of each MFMA (off the h critical path);
// C[1..3] never read (D[0] only is consumed).
// Scale folding (R2-verified math): sigmoid via r=rcp(1+exp2(a')), -L folded
// into weights for i,f,o; -2L for g so r_g=(tanh+1)/2; cs = -2L*c so
// tanh(c) = 2*rcp(1+exp2(cs)) - 1.
// R2 lesson: wall clock = 1024 steps x per-wave step time -> minimum work
// per wave (1 batch); batching 16/wave multiplied trans issue 16x (324us).

#define T_LEN 1024
#define BATCH 1024

typedef __fp16 h4 __attribute__((ext_vector_type(4)));
typedef float f4 __attribute__((ext_vector_type(4)));
typedef int i2 __attribute__((ext_vector_type(2)));

__device__ __forceinline__ float fexp2(float x) {
#if __has_builtin(__builtin_amdgcn_exp2f)
    return __builtin_amdgcn_exp2f(x);
#else
    return exp2f(x);
#endif
}
__device__ __forceinline__ float frcp(float x) {
#if __has_builtin(__builtin_amdgcn_rcpf)
    return __builtin_amdgcn_rcpf(x);
#else
    return 1.0f / x;
#endif
}
__device__ __forceinline__ float rlanef(float v, int l) {
    return __int_as_float(__builtin_amdgcn_readlane(__float_as_int(v), l));
}
// quad_perm [1,0,3,2]: swap adjacent lanes within each quad
__device__ __forceinline__ float quad_swap(float v) {
    return __int_as_float(
        __builtin_amdgcn_mov_dpp(__float_as_int(v), 0xB1, 0xf, 0xf, true));
}
__device__ __forceinline__ int pack_rtz(float lo, float hi) {
    return __builtin_bit_cast(int, __builtin_amdgcn_cvt_pkrtz(lo, hi));
}

__launch_bounds__(256)
__global__ void lstm_cls_kernel(const float* __restrict__ x,
                                const float* __restrict__ W_ih,
                                const float* __restrict__ W_hh,
                                const float* __restrict__ b_ih,
                                const float* __restrict__ b_hh,
                                const float* __restrict__ W_fc,
                                const float* __restrict__ b_fc,
                                float* __restrict__ out) {
    const int tid  = threadIdx.x;
    const int wave = tid >> 6;
    const int lane = tid & 63;
    const int b    = blockIdx.x * 4 + wave;   // one batch per wave
    const int c    = lane & 15;               // unit owned by this lane
    const int g    = lane >> 4;               // k/row group 0..3

    const float LOG2E = 1.44269504088896340736f;
    const float NEGL  = -LOG2E;
    const float NEG2L = -2.0f * LOG2E;
    const float POS2L =  2.0f * LOG2E;
    const float NEG4L = -4.0f * LOG2E;

    // ---- B fragments (const): B_q[k=4g+e][n=c] = s_q * W_hh[q*16+c][4g+e]
    h4 Bi, Bf, Bg, Bo;
    {
        const f4 wi = *(const f4*)(W_hh + (0 * 16 + c) * 16 + 4 * g);
        const f4 wf = *(const f4*)(W_hh + (1 * 16 + c) * 16 + 4 * g);
        const f4 wg = *(const f4*)(W_hh + (2 * 16 + c) * 16 + 4 * g);
        const f4 wo = *(const f4*)(W_hh + (3 * 16 + c) * 16 + 4 * g);
        #pragma unroll
        for (int e = 0; e < 4; ++e) {
            Bi[e] = (__fp16)(NEGL  * wi[e]);
            Bf[e] = (__fp16)(NEGL  * wf[e]);
            Bg[e] = (__fp16)(NEG2L * wg[e]);
            Bo[e] = (__fp16)(NEGL  * wo[e]);
        }
    }

    // ---- per-lane x-path constants (row = q*16 + c) ----
    const float KWi = NEGL  * W_ih[0 * 16 + c];
    const float KWf = NEGL  * W_ih[1 * 16 + c];
    const float KWg = NEG2L * W_ih[2 * 16 + c];
    const float KWo = NEGL  * W_ih[3 * 16 + c];
    const float KBi = NEGL  * (b_ih[0 * 16 + c] + b_hh[0 * 16 + c]);
    const float KBf = NEGL  * (b_ih[1 * 16 + c] + b_hh[1 * 16 + c]);
    const float KBg = NEG2L * (b_ih[2 * 16 + c] + b_hh[2 * 16 + c]);
    const float KBo = NEGL  * (b_ih[3 * 16 + c] + b_hh[3 * 16 + c]);

    // ---- bpermute byte addrs (loop-invariant): lane 4g and 4g+2 ----
    const int bp_lo = lane & 48;      // 16*g -> lane 4g   (P_{2g})
    const int bp_hi = bp_lo + 8;      //       -> lane 4g+2 (P_{2g+1})

    // ---- C fragments: only [0] written per step, [1..3] stay 0 (unread) ---
    f4 Ci = {0.f, 0.f, 0.f, 0.f};
    f4 Cf = {0.f, 0.f, 0.f, 0.f};
    f4 Cg = {0.f, 0.f, 0.f, 0.f};
    f4 Co = {0.f, 0.f, 0.f, 0.f};

    // ---- state ----
    float cs = 0.0f;   // cs = -2*log2e * c
    float hn = 0.0f;   // h of unit c (redundant over g)

    // ---- x preload: 16 VGPRs hold the whole sequence ----
    const float4* xv = (const float4*)(x + (size_t)b * T_LEN);
    const float4 xq0 = xv[lane];
    const float4 xq1 = xv[lane + 64];
    const float4 xq2 = xv[lane + 128];
    const float4 xq3 = xv[lane + 192];

    auto step = [&](float xb) {
        // x contribution into C[0] (h-independent, off the serial chain)
        Ci[0] = fmaf(xb, KWi, KBi);
        Cf[0] = fmaf(xb, KWf, KBf);
        Cg[0] = fmaf(xb, KWg, KBg);
        Co[0] = fmaf(xb, KWo, KBo);

        // pack h pairs: even lane 2t holds P_t = (h_{2t}, h_{2t+1})
        const float hx = quad_swap(hn);
        const int   hp = pack_rtz(hn, hx);

        // gather A-frag: A[e] = h[4g+e] (two packed pairs via bpermute)
        const int alo = __builtin_amdgcn_ds_bpermute(bp_lo, hp);
        const int ahi = __builtin_amdgcn_ds_bpermute(bp_hi, hp);
        i2 ai; ai[0] = alo; ai[1] = ahi;
        const h4 A = __builtin_bit_cast(h4, ai);

        // 4 broadcast-A MFMAs: D_q[*][c] = preact(gate q, unit c) + C_q[0]
        const f4 dg = __builtin_amdgcn_mfma_f32_16x16x16f16(A, Bg, Cg, 0, 0, 0);
        const f4 di = __builtin_amdgcn_mfma_f32_16x16x16f16(A, Bi, Ci, 0, 0, 0);
        const f4 df = __builtin_amdgcn_mfma_f32_16x16x16f16(A, Bf, Cf, 0, 0, 0);
        const f4 dq = __builtin_amdgcn_mfma_f32_16x16x16f16(A, Bo, Co, 0, 0, 0);

        // lane-local activations + cell update (R2-verified math)
        const float rg = frcp(1.0f + fexp2(dg[0]));
        const float ri = frcp(1.0f + fexp2(di[0]));
        const float rf = frcp(1.0f + fexp2(df[0]));
        const float ro = frcp(1.0f + fexp2(dq[0]));

        const float term = ri * fmaf(rg, NEG4L, POS2L);
        cs = fmaf(rf, cs, term);
        const float rt = frcp(1.0f + fexp2(cs));
        hn = fmaf(ro + ro, rt, -ro);
    };

    #pragma unroll
    for (int k = 0; k < 4; ++k) {
        const float4 xk = (k == 0) ? xq0 : (k == 1) ? xq1
                        : (k == 2) ? xq2 : xq3;
        #pragma unroll 2
        for (int r = 0; r < 64; ++r) {
            step(rlanef(xk.x, r));
            step(rlanef(xk.y, r));
            step(rlanef(xk.z, r));
            step(rlanef(xk.w, r));
        }
    }

    // ---- epilogue: logits[b, cc] = b_fc[cc] + W_fc[cc,:] . h ----
    float hv[16];
    #pragma unroll
    for (int k = 0; k < 16; ++k) hv[k] = rlanef(hn, k);

    if (lane < 6) {
        const float* wf = W_fc + lane * 16;
        float acc = b_fc[lane];
        #pragma unroll
        for (int k = 0; k < 16; ++k) acc = fmaf(wf[k], hv[k], acc);
        out[b * 6 + lane] = acc;
    }
}

extern "C" void kernel_launch(void* const* d_in, const int* in_sizes, int n_in,
                              void* d_out, int out_size, void* d_ws, size_t ws_size,
                              hipStream_t stream) {
    const float* x    = (const float*)d_in[0];
    const float* W_ih = (const float*)d_in[1];
    const float* W_hh = (const float*)d_in[2];
    const float* b_ih = (const float*)d_in[3];
    const float* b_hh = (const float*)d_in[4];
    const float* W_fc = (const float*)d_in[5];
    const float* b_fc = (const float*)d_in[6];
    float* out = (float*)d_out;

    lstm_cls_kernel<<<BATCH / 4, 256, 0, stream>>>(x, W_ih, W_hh, b_ih, b_hh,
                                                   W_fc, b_fc, out);
}

// Round 4
// 221.992 us; speedup vs baseline: 1.7238x; 1.0591x over previous
//
#include <hip/hip_runtime.h>

// LSTMClassifier: B=1024, T=1024, H=16, C=6
// V4 = 156us scalar baseline step + K=2 in-wave batch interleave.
// R3 lesson: wall = 1024 x per-step CHAIN time; cross-batch parallelism
// (waves/SIMD, batches-in-MFMA) cannot shorten one wave's serial chain.
// MFMA front-end (V3) has MORE chain latency than readlane/fdot2 (429 vs
// 366 cy/step). The only wall-cutting lever left: interleave K independent
// recurrences IN ONE WAVE so batch A's dependency stalls are filled by
// batch B's issue slots (step body has NO s_waitcnt -> all stalls fillable).
// Issue ~110 cy/step, stall ~250 -> K=2 round ~ max(220..260, chain) ->
// ~130-150 cy/batch-step. K=3 would be issue-bound (330) - worse.
// Step body (unchanged from 156us kernel): lane 4j+q owns gate q of unit j;
// matvec = 8 readlane + 8 v_dot2_f32_f16 (two 4-deep chains); exp-split
// exp2(A+B)=exp2(A)*exp2(B); kk folded into weights; cs = -2*log2e*c;
// x front-end hoisted off the serial chain.

#define T_LEN 1024
#define BATCH 1024

typedef _Float16 h2v __attribute__((ext_vector_type(2)));

__device__ __forceinline__ float rlanef(float v, int l) {
    return __int_as_float(__builtin_amdgcn_readlane(__float_as_int(v), l));
}
__device__ __forceinline__ int rlanei(int v, int l) {
    return __builtin_amdgcn_readlane(v, l);
}

template<int CTRL>
__device__ __forceinline__ float movdpp(float v) {
    return __int_as_float(
        __builtin_amdgcn_mov_dpp(__float_as_int(v), CTRL, 0xf, 0xf, true));
}

template<int N>
__device__ __forceinline__ float quad_bcastf(float v) {
    constexpr int ctrl = N * 0x55;  // replicate lane N of each quad
    return __int_as_float(
        __builtin_amdgcn_mov_dpp(__float_as_int(v), ctrl, 0xf, 0xf, true));
}

__device__ __forceinline__ float fexp2(float x) {
#if __has_builtin(__builtin_amdgcn_exp2f)
    return __builtin_amdgcn_exp2f(x);
#else
    return exp2f(x);
#endif
}
__device__ __forceinline__ float frcp(float x) {
#if __has_builtin(__builtin_amdgcn_rcpf)
    return __builtin_amdgcn_rcpf(x);
#else
    return 1.0f / x;
#endif
}

__device__ __forceinline__ float fdot2(h2v a, h2v b, float c) {
#if __has_builtin(__builtin_amdgcn_fdot2)
    return __builtin_amdgcn_fdot2(a, b, c, false);
#else
    return fmaf((float)a.x, (float)b.x, fmaf((float)a.y, (float)b.y, c));
#endif
}

__device__ __forceinline__ int pack_rtz(float lo, float hi) {
#if __has_builtin(__builtin_amdgcn_cvt_pkrtz)
    return __builtin_bit_cast(int, __builtin_amdgcn_cvt_pkrtz(lo, hi));
#else
    h2v p; p.x = (_Float16)lo; p.y = (_Float16)hi;
    return __builtin_bit_cast(int, p);
#endif
}

__device__ __forceinline__ h2v as_h2(int bits) {
    return __builtin_bit_cast(h2v, bits);
}

__launch_bounds__(256)
__global__ void lstm_cls_kernel(const float* __restrict__ x,
                                const float* __restrict__ W_ih,
                                const float* __restrict__ W_hh,
                                const float* __restrict__ b_ih,
                                const float* __restrict__ b_hh,
                                const float* __restrict__ W_fc,
                                const float* __restrict__ b_fc,
                                float* __restrict__ out) {
    const int tid  = threadIdx.x;
    const int wave = tid >> 6;
    const int lane = tid & 63;
    const int b0   = blockIdx.x * 8 + wave * 2;  // two batches per wave
    const int b1   = b0 + 1;
    const int j    = lane >> 2;               // hidden unit 0..15
    const int q    = lane & 3;                // 0=i, 1=f, 2=g, 3=o
    const int row  = q * 16 + j;              // row in [4H] (PyTorch order)

    const float LOG2E = 1.44269504088896340736f;
    const float NEG2L = -2.0f * LOG2E;
    const float NEG4L = -4.0f * LOG2E;
    // kk folded into weights: matvec emits kk*a; r = 1/(1+exp2(kk*a))
    // q!=2 -> sigmoid(a); q==2 -> (tanh(a)+1)/2
    const float kk = (q == 2) ? NEG2L : -LOG2E;

    // f16 weight pairs matching the h-pair pattern (k0, k0+2):
    // (0,2)(1,3)(4,6)(5,7)(8,10)(9,11)(12,14)(13,15)
    const float* wr = W_hh + row * 16;
    h2v wp0, wp1, wp2, wp3, wp4, wp5, wp6, wp7;
    {
        #define MKWP(WP, K0) \
            WP.x = (_Float16)(kk * wr[K0]); WP.y = (_Float16)(kk * wr[(K0) + 2]);
        MKWP(wp0, 0) MKWP(wp1, 1) MKWP(wp2, 4) MKWP(wp3, 5)
        MKWP(wp4, 8) MKWP(wp5, 9) MKWP(wp6, 12) MKWP(wp7, 13)
        #undef MKWP
    }

    const float kwih  = kk * W_ih[row];
    const float kbias = kk * (b_ih[row] + b_hh[row]);

    // Preload both batches' x sequences (16 VGPRs each)
    const float4* xv0 = (const float4*)(x + (size_t)b0 * T_LEN);
    const float4* xv1 = (const float4*)(x + (size_t)b1 * T_LEN);
    const float4 xa0 = xv0[lane];
    const float4 xa1 = xv0[lane + 64];
    const float4 xa2 = xv0[lane + 128];
    const float4 xa3 = xv0[lane + 192];
    const float4 xb0 = xv1[lane];
    const float4 xb1 = xv1[lane + 64];
    const float4 xb2 = xv1[lane + 128];
    const float4 xb3 = xv1[lane + 192];

    float h0 = 0.0f, cs0 = 0.0f;   // batch b0 state (cs = -2*log2e*c)
    float h1 = 0.0f, cs1 = 0.0f;   // batch b1 state

    auto step = [&](float& h, float& cs, float ax) {
        // (h_j, h_{j+-2}) f16 pair: partner via ROW_ROR:8, pack with pkrtz
        const float hr = movdpp<0x128>(h);
        const int hb = pack_rtz(h, hr);

        // q=0 source lanes: 0->(h0,h2) 4->(h1,h3) 16->(h4,h6) 20->(h5,h7)
        //                   32->(h8,h10) 36->(h9,h11) 48->(h12,h14) 52->(h13,h15)
        const int s0 = rlanei(hb, 0);
        const int s1 = rlanei(hb, 4);
        const int s2 = rlanei(hb, 16);
        const int s3 = rlanei(hb, 20);
        const int s4 = rlanei(hb, 32);
        const int s5 = rlanei(hb, 36);
        const int s6 = rlanei(hb, 48);
        const int s7 = rlanei(hb, 52);

        float A = fdot2(wp0, as_h2(s0), ax);
        float B = fdot2(wp1, as_h2(s1), 0.0f);
        A = fdot2(wp2, as_h2(s2), A);
        B = fdot2(wp3, as_h2(s3), B);
        A = fdot2(wp4, as_h2(s4), A);
        B = fdot2(wp5, as_h2(s5), B);
        A = fdot2(wp6, as_h2(s6), A);
        B = fdot2(wp7, as_h2(s7), B);

        // exp-split: exp2(A+B) = exp2(A)*exp2(B)
        const float eA = fexp2(A);
        const float eB = fexp2(B);
        const float e  = eA * eB;
        const float r  = frcp(1.0f + e);

        // quad gather (r0 = self; only q=0 lanes' h/cs are ever read)
        const float r1 = quad_bcastf<1>(r);   // f (sigmoid)
        const float r2 = quad_bcastf<2>(r);   // (tanh g + 1)/2
        const float r3 = quad_bcastf<3>(r);   // o (sigmoid)

        // cs = r1*cs + NEG2L*r*(2*r2-1) = fma(r1, cs, fma(m2, r2, -m))
        const float m  = NEG2L * r;           // DPP shadow
        const float m2 = NEG4L * r;           // DPP shadow
        const float term = fmaf(m2, r2, -m);
        cs = fmaf(r1, cs, term);              // cs = -2L * c

        // h = o*tanh(c) = 2*o/(1+exp2(cs)) - o
        const float et = fexp2(cs);
        const float rt = frcp(1.0f + et);
        const float t3 = r3 + r3;             // exp shadow
        h = fmaf(t3, rt, -r3);
    };

    #pragma unroll
    for (int k = 0; k < 4; ++k) {
        const float4 xk0 = (k == 0) ? xa0 : (k == 1) ? xa1
                         : (k == 2) ? xa2 : xa3;
        const float4 xk1 = (k == 0) ? xb0 : (k == 1) ? xb1
                         : (k == 2) ? xb2 : xb3;
        #pragma unroll 2
        for (int r = 0; r < 64; ++r) {
            // x front-end hoisted off the serial h-chains (h-independent)
            const float a0x = fmaf(kwih, rlanef(xk0.x, r), kbias);
            const float a0y = fmaf(kwih, rlanef(xk0.y, r), kbias);
            const float a0z = fmaf(kwih, rlanef(xk0.z, r), kbias);
            const float a0w = fmaf(kwih, rlanef(xk0.w, r), kbias);
            const float a1x = fmaf(kwih, rlanef(xk1.x, r), kbias);
            const float a1y = fmaf(kwih, rlanef(xk1.y, r), kbias);
            const float a1z = fmaf(kwih, rlanef(xk1.z, r), kbias);
            const float a1w = fmaf(kwih, rlanef(xk1.w, r), kbias);
            // K=2 interleave: batch b1's issue fills b0's chain stalls
            step(h0, cs0, a0x); step(h1, cs1, a1x);
            step(h0, cs0, a0y); step(h1, cs1, a1y);
            step(h0, cs0, a0z); step(h1, cs1, a1z);
            step(h0, cs0, a0w); step(h1, cs1, a1w);
        }
    }

    // Epilogue: logits[b, cc] = b_fc[cc] + sum_k W_fc[cc,k] * h_k
    float hv0[16], hv1[16];
    #pragma unroll
    for (int k = 0; k < 16; ++k) hv0[k] = rlanef(h0, 4 * k);
    #pragma unroll
    for (int k = 0; k < 16; ++k) hv1[k] = rlanef(h1, 4 * k);

    if (lane < 6) {
        const float* wf = W_fc + lane * 16;
        float acc0 = b_fc[lane];
        float acc1 = acc0;
        #pragma unroll
        for (int k = 0; k < 16; ++k) {
            acc0 = fmaf(wf[k], hv0[k], acc0);
            acc1 = fmaf(wf[k], hv1[k], acc1);
        }
        out[b0 * 6 + lane] = acc0;
        out[b1 * 6 + lane] = acc1;
    }
}

extern "C" void kernel_launch(void* const* d_in, const int* in_sizes, int n_in,
                              void* d_out, int out_size, void* d_ws, size_t ws_size,
                              hipStream_t stream) {
    const float* x    = (const float*)d_in[0];
    const float* W_ih = (const float*)d_in[1];
    const float* W_hh = (const float*)d_in[2];
    const float* b_ih = (const float*)d_in[3];
    const float* b_hh = (const float*)d_in[4];
    const float* W_fc = (const float*)d_in[5];
    const float* b_fc = (const float*)d_in[6];
    float* out = (float*)d_out;

    lstm_cls_kernel<<<BATCH / 8, 256, 0, stream>>>(x, W_ih, W_hh, b_ih, b_hh,
                                                   W_fc, b_fc, out);
}

// Round 6
// 194.581 us; speedup vs baseline: 1.9666x; 1.1409x over previous
//
#include <hip/hip_runtime.h>

// LSTMClassifier: B=1024, T=1024, H=16, C=6
// V6 = V5 with the DPP direction fix. R5 lesson (HW fact, two independent
// confirmations): row_ror:n delivers lane i <- lane (i-n) mod 16 (data
// rotates toward HIGHER lanes; GPUOpen prefix-scan convention). V5's
// ROW_ROR:4 paired (h_u, h_{u-1}) -> scrambled matvec (absmax 4.5e-2).
// Fix: ROW_ROR:12 (0x12C) = lane i <- lane (i+4) mod 16 -> (h_u, h_{u+1}).
// Structure (V5): 1 batch/wave, 1024 waves; k-sliced matvec + quad
// all-reduce; gate math fully lane-local.
//   lane L = (unit u = L>>2, slice s = L&3)
//   lane computes partials of ALL 4 gates of unit u over k in {4s..4s+3}
//   (8 fdot2, depth-2 chains), then 2-level quad butterfly (DPP xor1/xor2
//   adds) -> every lane holds all 4 FULL gate preacts locally.
// vs 156us baseline chain: removes 8 hazard-stalled v_readlane (-> 1 DPP +
// pack + 2 loop-invariant ds_bpermute), removes 3 post-rcp DPP broadcasts,
// dot chain depth 4 -> 2.
// h exchange: p = pkrtz(h, ror12(h)) -> quad q of row R holds
// (h_{4R+q}, h_{4R+(q+1)%4}); lane pulls row s's quad0 (addr 64s) and
// quad2 (addr 64s+32) via bpermute -> (h_4s,h_{4s+1}),(h_{4s+2},h_{4s+3}).
// x/bias seed folded at 0.25x per slice lane: quad-sum reconstructs exactly.
// Scale folding (R2-verified): sigmoid r = rcp(1+exp2(a')), -L folded for
// i,f,o; -2L for g so rg=(tanh+1)/2; cs = -2L*c so tanh(c)=2*rcp(1+exp2(cs))-1.

#define T_LEN 1024
#define BATCH 1024

typedef _Float16 h2v __attribute__((ext_vector_type(2)));

__device__ __forceinline__ float rlanef(float v, int l) {
    return __int_as_float(__builtin_amdgcn_readlane(__float_as_int(v), l));
}

template<int CTRL>
__device__ __forceinline__ float movdppf(float v) {
    return __int_as_float(
        __builtin_amdgcn_mov_dpp(__float_as_int(v), CTRL, 0xf, 0xf, true));
}

__device__ __forceinline__ float fexp2(float x) {
#if __has_builtin(__builtin_amdgcn_exp2f)
    return __builtin_amdgcn_exp2f(x);
#else
    return exp2f(x);
#endif
}
__device__ __forceinline__ float frcp(float x) {
#if __has_builtin(__builtin_amdgcn_rcpf)
    return __builtin_amdgcn_rcpf(x);
#else
    return 1.0f / x;
#endif
}

__device__ __forceinline__ float fdot2(h2v a, h2v b, float c) {
#if __has_builtin(__builtin_amdgcn_fdot2)
    return __builtin_amdgcn_fdot2(a, b, c, false);
#else
    return fmaf((float)a.x, (float)b.x, fmaf((float)a.y, (float)b.y, c));
#endif
}

__device__ __forceinline__ int pack_rtz(float lo, float hi) {
#if __has_builtin(__builtin_amdgcn_cvt_pkrtz)
    return __builtin_bit_cast(int, __builtin_amdgcn_cvt_pkrtz(lo, hi));
#else
    h2v p; p.x = (_Float16)lo; p.y = (_Float16)hi;
    return __builtin_bit_cast(int, p);
#endif
}

__device__ __forceinline__ h2v as_h2(int bits) {
    return __builtin_bit_cast(h2v, bits);
}

__launch_bounds__(256)
__global__ void lstm_cls_kernel(const float* __restrict__ x,
                                const float* __restrict__ W_ih,
                                const float* __restrict__ W_hh,
                                const float* __restrict__ b_ih,
                                const float* __restrict__ b_hh,
                                const float* __restrict__ W_fc,
                                const float* __restrict__ b_fc,
                                float* __restrict__ out) {
    const int tid  = threadIdx.x;
    const int wave = tid >> 6;
    const int lane = tid & 63;
    const int b    = blockIdx.x * 4 + wave;   // one batch per wave
    const int u    = lane >> 2;               // hidden unit 0..15
    const int s    = lane & 3;                // k-slice: k in {4s..4s+3}

    const float LOG2E = 1.44269504088896340736f;
    const float NEGL  = -LOG2E;
    const float NEG2L = -2.0f * LOG2E;
    const float POS2L =  2.0f * LOG2E;
    const float NEG4L = -4.0f * LOG2E;

    // ---- weight pairs: gate q row = q*16+u, k = 4s..4s+3 (consecutive) ----
    const float* wr_i = W_hh + (0 * 16 + u) * 16 + 4 * s;
    const float* wr_f = W_hh + (1 * 16 + u) * 16 + 4 * s;
    const float* wr_g = W_hh + (2 * 16 + u) * 16 + 4 * s;
    const float* wr_o = W_hh + (3 * 16 + u) * 16 + 4 * s;
    h2v wpi0, wpi1, wpf0, wpf1, wpg0, wpg1, wpo0, wpo1;
    wpi0.x = (_Float16)(NEGL  * wr_i[0]); wpi0.y = (_Float16)(NEGL  * wr_i[1]);
    wpi1.x = (_Float16)(NEGL  * wr_i[2]); wpi1.y = (_Float16)(NEGL  * wr_i[3]);
    wpf0.x = (_Float16)(NEGL  * wr_f[0]); wpf0.y = (_Float16)(NEGL  * wr_f[1]);
    wpf1.x = (_Float16)(NEGL  * wr_f[2]); wpf1.y = (_Float16)(NEGL  * wr_f[3]);
    wpg0.x = (_Float16)(NEG2L * wr_g[0]); wpg0.y = (_Float16)(NEG2L * wr_g[1]);
    wpg1.x = (_Float16)(NEG2L * wr_g[2]); wpg1.y = (_Float16)(NEG2L * wr_g[3]);
    wpo0.x = (_Float16)(NEGL  * wr_o[0]); wpo0.y = (_Float16)(NEGL  * wr_o[1]);
    wpo1.x = (_Float16)(NEGL  * wr_o[2]); wpo1.y = (_Float16)(NEGL  * wr_o[3]);

    // ---- x/bias constants, pre-scaled by 0.25 (seeded in all 4 slice
    //      lanes; quad-sum reconstructs the full term exactly once) ----
    const float QT = 0.25f;
    const float KWi = QT * NEGL  * W_ih[0 * 16 + u];
    const float KWf = QT * NEGL  * W_ih[1 * 16 + u];
    const float KWg = QT * NEG2L * W_ih[2 * 16 + u];
    const float KWo = QT * NEGL  * W_ih[3 * 16 + u];
    const float KBi = QT * NEGL  * (b_ih[0 * 16 + u] + b_hh[0 * 16 + u]);
    const float KBf = QT * NEGL  * (b_ih[1 * 16 + u] + b_hh[1 * 16 + u]);
    const float KBg = QT * NEG2L * (b_ih[2 * 16 + u] + b_hh[2 * 16 + u]);
    const float KBo = QT * NEGL  * (b_ih[3 * 16 + u] + b_hh[3 * 16 + u]);

    // ---- bpermute byte addrs (loop-invariant): row s, quad0 / quad2 ----
    const int addr_lo = s * 64;        // lane 16s   -> (h_{4s},   h_{4s+1})
    const int addr_hi = addr_lo + 32;  // lane 16s+8 -> (h_{4s+2}, h_{4s+3})

    // ---- x preload: 16 VGPRs hold the whole sequence ----
    const float4* xv = (const float4*)(x + (size_t)b * T_LEN);
    const float4 xq0 = xv[lane];
    const float4 xq1 = xv[lane + 64];
    const float4 xq2 = xv[lane + 128];
    const float4 xq3 = xv[lane + 192];

    float hn = 0.0f;   // h_u (replicated over the quad)
    float cs = 0.0f;   // cs = -2*log2e * c_u

    auto step = [&](float xb) {
        // x front-end (h-independent, off the serial chain)
        const float axi = fmaf(xb, KWi, KBi);
        const float axf = fmaf(xb, KWf, KBf);
        const float axg = fmaf(xb, KWg, KBg);
        const float axo = fmaf(xb, KWo, KBo);

        // h exchange: ROW_ROR:12 -> lane i gets lane (i+4)%16 (unit u+1);
        // pkrtz packs (h_u, h_{u+1}); bpermute pulls row s's quad0/quad2
        const float tro = movdppf<0x12C>(hn);            // ROW_ROR:12
        const int   hp  = pack_rtz(hn, tro);
        const int   alo = __builtin_amdgcn_ds_bpermute(addr_lo, hp);
        const int   ahi = __builtin_amdgcn_ds_bpermute(addr_hi, hp);
        const h2v   hlo = as_h2(alo);
        const h2v   hhi = as_h2(ahi);

        // per-lane partial dots (depth 2), seeded with 0.25x x-term
        float Pg = fdot2(wpg1, hhi, fdot2(wpg0, hlo, axg));
        float Pi = fdot2(wpi1, hhi, fdot2(wpi0, hlo, axi));
        float Pf = fdot2(wpf1, hhi, fdot2(wpf0, hlo, axf));
        float Po = fdot2(wpo1, hhi, fdot2(wpo0, hlo, axo));

        // quad all-reduce (xor1 = quad_perm[1,0,3,2], xor2 = [2,3,0,1])
        Pg += movdppf<0xB1>(Pg);  Pg += movdppf<0x4E>(Pg);
        Pi += movdppf<0xB1>(Pi);  Pi += movdppf<0x4E>(Pi);
        Pf += movdppf<0xB1>(Pf);  Pf += movdppf<0x4E>(Pf);
        Po += movdppf<0xB1>(Po);  Po += movdppf<0x4E>(Po);

        // lane-local activations (no cross-lane from here on)
        const float rg = frcp(1.0f + fexp2(Pg));   // (tanh g + 1)/2
        const float ri = frcp(1.0f + fexp2(Pi));   // sigmoid i
        const float rf = frcp(1.0f + fexp2(Pf));   // sigmoid f
        const float ro = frcp(1.0f + fexp2(Po));   // sigmoid o

        // cs = rf*cs + NEG2L*ri*(2*rg - 1)
        const float t1   = fmaf(rg, NEG4L, POS2L);
        const float term = ri * t1;
        cs = fmaf(rf, cs, term);

        // h = o*tanh(c) = 2*o*rcp(1+exp2(cs)) - o
        const float rt = frcp(1.0f + fexp2(cs));
        hn = fmaf(ro + ro, rt, -ro);
    };

    #pragma unroll
    for (int k = 0; k < 4; ++k) {
        const float4 xk = (k == 0) ? xq0 : (k == 1) ? xq1
                        : (k == 2) ? xq2 : xq3;
        #pragma unroll 2
        for (int r = 0; r < 64; ++r) {
            step(rlanef(xk.x, r));
            step(rlanef(xk.y, r));
            step(rlanef(xk.z, r));
            step(rlanef(xk.w, r));
        }
    }

    // ---- epilogue: logits[b, cc] = b_fc[cc] + W_fc[cc,:] . h ----
    float hv[16];
    #pragma unroll
    for (int k = 0; k < 16; ++k) hv[k] = rlanef(hn, 4 * k);

    if (lane < 6) {
        const float* wf = W_fc + lane * 16;
        float acc = b_fc[lane];
        #pragma unroll
        for (int k = 0; k < 16; ++k) acc = fmaf(wf[k], hv[k], acc);
        out[b * 6 + lane] = acc;
    }
}

extern "C" void kernel_launch(void* const* d_in, const int* in_sizes, int n_in,
                              void* d_out, int out_size, void* d_ws, size_t ws_size,
                              hipStream_t stream) {
    const float* x    = (const float*)d_in[0];
    const float* W_ih = (const float*)d_in[1];
    const float* W_hh = (const float*)d_in[2];
    const float* b_ih = (const float*)d_in[3];
    const float* b_hh = (const float*)d_in[4];
    const float* W_fc = (const float*)d_in[5];
    const float* b_fc = (const float*)d_in[6];
    float* out = (float*)d_out;

    lstm_cls_kernel<<<BATCH / 4, 256, 0, stream>>>(x, W_ih, W_hh, b_ih, b_hh,
                                                   W_fc, b_fc, out);
}